// Round 12
// baseline (2094.985 us; speedup 1.0000x reference)
//
#include <hip/hip_runtime.h>
#include <hip/hip_bf16.h>
#include <hip/hip_cooperative_groups.h>

namespace cg = cooperative_groups;

#define IN_DIM  512
#define HID_DIM 256
#define OUT_DIM 64

typedef __attribute__((ext_vector_type(8))) short bf16x8;
typedef __attribute__((ext_vector_type(4))) float f32x4;

static __device__ __forceinline__ ushort f2b(float f) {
    __hip_bfloat16 b = __float2bfloat16(f);
    return *reinterpret_cast<ushort*>(&b);
}
static __device__ __forceinline__ float b2f_lo(uint u) {
    union { uint u; float f; } t; t.u = u << 16; return t.f;
}
static __device__ __forceinline__ float b2f_hi(uint u) {
    union { uint u; float f; } t; t.u = u & 0xFFFF0000u; return t.f;
}
static __device__ __forceinline__ uint packbf(float x, float y) {
    return (uint)f2b(x) | ((uint)f2b(y) << 16);
}

#define GLOAD16(g, l) __builtin_amdgcn_global_load_lds(                      \
    (const __attribute__((address_space(1))) void*)(g),                      \
    (__attribute__((address_space(3))) void*)(l), 16, 0, 0)

// ---------------- fp32 -> bf16 bulk convert (W1 only) ----------------

__global__ __launch_bounds__(256) void f2b_kernel(const float* __restrict__ in,
                                                  ushort* __restrict__ out, int n8) {
    for (int i = blockIdx.x * 256 + threadIdx.x; i < n8; i += gridDim.x * 256) {
        float4 a = *reinterpret_cast<const float4*>(&in[(size_t)i * 8]);
        float4 b = *reinterpret_cast<const float4*>(&in[(size_t)i * 8 + 4]);
        ushort4 lo = make_ushort4(f2b(a.x), f2b(a.y), f2b(a.z), f2b(a.w));
        ushort4 hi = make_ushort4(f2b(b.x), f2b(b.y), f2b(b.z), f2b(b.w));
        *reinterpret_cast<ushort4*>(&out[(size_t)i * 8])     = lo;
        *reinterpret_cast<ushort4*>(&out[(size_t)i * 8 + 4]) = hi;
    }
}

// ---------------- CSR build ----------------

__global__ void hist_kernel(const int* __restrict__ ei, int* __restrict__ deg, int E) {
    int e = blockIdx.x * 256 + threadIdx.x;
    if (e < E) atomicAdd(&deg[ei[E + e]], 1);
}

__global__ __launch_bounds__(256) void scanA_kernel(const int* __restrict__ deg,
                                                    int* __restrict__ offs,
                                                    int* __restrict__ bsum, int N) {
    __shared__ int sh[256];
    int tid = threadIdx.x;
    int i = blockIdx.x * 256 + tid;
    int v = (i < N) ? deg[i] : 0;
    sh[tid] = v;
    __syncthreads();
#pragma unroll
    for (int off = 1; off < 256; off <<= 1) {
        int t = (tid >= off) ? sh[tid - off] : 0;
        __syncthreads();
        sh[tid] += t;
        __syncthreads();
    }
    if (i < N) offs[i] = sh[tid] - v;
    if (tid == 255) bsum[blockIdx.x] = sh[255];
}

__global__ __launch_bounds__(256) void scanB_kernel(int* __restrict__ bsum, int nb) {
    __shared__ int sh[256];
    int tid = threadIdx.x;
    int v = (tid < nb) ? bsum[tid] : 0;
    sh[tid] = v;
    __syncthreads();
#pragma unroll
    for (int off = 1; off < 256; off <<= 1) {
        int t = (tid >= off) ? sh[tid - off] : 0;
        __syncthreads();
        sh[tid] += t;
        __syncthreads();
    }
    if (tid < nb) bsum[tid] = sh[tid] - v;
}

__global__ __launch_bounds__(256) void scanC_kernel(const int* __restrict__ deg,
                                                    const int* __restrict__ bsum,
                                                    int* __restrict__ offs,
                                                    float* __restrict__ dinv,
                                                    int N, int E) {
    int i = blockIdx.x * 256 + threadIdx.x;
    if (i < N) {
        offs[i] += bsum[i >> 8];
        dinv[i] = rsqrtf((float)(deg[i] + 1));
    }
    if (i == 0) offs[N] = E;
}

// edat[pos] = src(u16) | f2b(w)<<16  -- 4B per edge
__global__ void fill_kernel(const int* __restrict__ ei, const int* __restrict__ offs,
                            int* __restrict__ cursor, const float* __restrict__ dinv,
                            uint* __restrict__ edat, int E) {
    int e = blockIdx.x * 256 + threadIdx.x;
    if (e < E) {
        int s = ei[e];
        int d = ei[E + e];
        int pos = offs[d] + atomicAdd(&cursor[d], 1);
        edat[pos] = (uint)s | ((uint)f2b(dinv[d] * dinv[s]) << 16);
    }
}

// ---------------- GEMM1 (r6-best, measured 64us): BK=64 single-buffer ----------
// fp32 A read directly via global_load_lds(16B); XOR-swizzled LDS; 2-barrier loop.

__global__ __launch_bounds__(256) void gemm1_f32a(const float* __restrict__ A,
                                                  const ushort* __restrict__ B,
                                                  const float* __restrict__ bias,
                                                  ushort* __restrict__ C, int M) {
    constexpr int K = IN_DIM;       // 512
    constexpr int NK = K / 64;      // 8 K-steps
    __shared__ float  Asf[128 * 64];   // 32KB fp32 A-tile
    __shared__ ushort Bs[128 * 64];    // 16KB bf16 B-tile

    const int tid  = threadIdx.x;
    const int lane = tid & 63;
    const int wid  = tid >> 6;
    const int wm = wid >> 1, wn = wid & 1;
    const int m0 = blockIdx.y * 128;
    const int n0 = blockIdx.x * 128;
    const int l15 = lane & 15;
    const int lq  = lane >> 4;

    // A staging: instr covers 4 rows x 16 16B-slots; swizzle at 32B-pair level.
    const int a_r   = lane >> 4;          // row within instr 0..3
    const int a_s16 = lane & 15;          // 16B slot 0..15
    const int a_pair = a_s16 >> 1, a_sub = a_s16 & 1;
    // B staging: instr covers 8 rows x 8 16B-slots; swizzle at 16B level.
    const int srow  = lane >> 3;
    const int sslot = (lane & 7) ^ srow;

    f32x4 acc[4][4];
#pragma unroll
    for (int i = 0; i < 4; ++i)
#pragma unroll
        for (int j = 0; j < 4; ++j) acc[i][j] = (f32x4)0.0f;

    for (int ks = 0; ks < NK; ++ks) {
        const int k0 = ks * 64;
        // B: 4 instrs/wave
#pragma unroll
        for (int q = 0; q < 4; ++q) {
            const int rbase = (wid * 4 + q) * 8;
            const int row = rbase + srow;
            const ushort* gb = B + (size_t)(n0 + row) * K + k0 + sslot * 8;
            GLOAD16(gb, &Bs[rbase * 64]);
        }
        // A: 8 instrs/wave (fp32)
#pragma unroll
        for (int q = 0; q < 8; ++q) {
            const int rbase = (wid * 8 + q) * 4;
            const int row = rbase + a_r;
            int am = m0 + row; if (am >= M) am = M - 1;
            const int col = k0 + ((a_pair ^ (row & 7)) << 3) + (a_sub << 2);
            const float* ga = A + (size_t)am * K + col;
            GLOAD16(ga, &Asf[rbase * 64]);
        }
        __syncthreads();
#pragma unroll
        for (int kk = 0; kk < 2; ++kk) {
            const int p = kk * 4 + lq;    // 32B pair slot = 8 elements
            bf16x8 af[4], bf[4];
#pragma unroll
            for (int f = 0; f < 4; ++f) {
                const int ar = wm * 64 + f * 16 + l15;
                const int fi = ar * 64 + ((p ^ (ar & 7)) << 3);
                f32x4 v0 = *reinterpret_cast<const f32x4*>(&Asf[fi]);
                f32x4 v1 = *reinterpret_cast<const f32x4*>(&Asf[fi + 4]);
                bf16x8 a;
                a[0] = (short)f2b(v0[0]); a[1] = (short)f2b(v0[1]);
                a[2] = (short)f2b(v0[2]); a[3] = (short)f2b(v0[3]);
                a[4] = (short)f2b(v1[0]); a[5] = (short)f2b(v1[1]);
                a[6] = (short)f2b(v1[2]); a[7] = (short)f2b(v1[3]);
                af[f] = a;
                const int br = wn * 64 + f * 16 + l15;
                bf[f] = *reinterpret_cast<const bf16x8*>(&Bs[br * 64 + ((p ^ (br & 7)) << 3)]);
            }
#pragma unroll
            for (int i = 0; i < 4; ++i)
#pragma unroll
                for (int j = 0; j < 4; ++j)
                    acc[i][j] = __builtin_amdgcn_mfma_f32_16x16x32_bf16(af[i], bf[j], acc[i][j], 0, 0, 0);
        }
        __syncthreads();
    }

    const int lr = lq * 4;
#pragma unroll
    for (int nf = 0; nf < 4; ++nf) {
        int col = n0 + wn * 64 + nf * 16 + l15;
        float bv = bias[col];
#pragma unroll
        for (int mf = 0; mf < 4; ++mf) {
#pragma unroll
            for (int j = 0; j < 4; ++j) {
                int row = m0 + wm * 64 + mf * 16 + lr + j;
                if (row < M) {
                    float v = fmaxf(acc[mf][nf][j] + bv, 0.f);
                    C[(size_t)row * HID_DIM + col] = f2b(v);
                }
            }
        }
    }
}

// ---------------- GEMM2: hb[M,64] = bf16(h1_bf16[M,256] @ W2[64,256]^T + b2) ----

#define LDT 40

__global__ __launch_bounds__(256) void gemm2_bf16(const ushort* __restrict__ A,
                                                  const float* __restrict__ B,
                                                  const float* __restrict__ bias,
                                                  ushort* __restrict__ Cb,
                                                  int M) {
    constexpr int K = HID_DIM;
    constexpr int NK = K / 32;
    __shared__ ushort As[128 * LDT];
    __shared__ ushort Bs[64 * LDT];

    const int tid = threadIdx.x;
    const int lane = tid & 63;
    const int wid = tid >> 6;
    const int wm = wid >> 1, wn = wid & 1;
    const int m0 = blockIdx.x * 128;
    const int l15 = lane & 15;
    const int koff = (lane >> 4) * 8;

    f32x4 acc[4][2];
#pragma unroll
    for (int i = 0; i < 4; ++i)
#pragma unroll
        for (int j = 0; j < 2; ++j) acc[i][j] = (f32x4)0.0f;

    uint4 rawA[2];
    float4 rbv[2];
#pragma unroll
    for (int i = 0; i < 2; ++i) {
        int slot = tid + i * 256;
        int rowA = slot >> 2, c8 = (slot & 3) << 3;
        int m = m0 + rowA;
        rawA[i] = (m < M) ? *reinterpret_cast<const uint4*>(&A[(size_t)m * K + c8])
                          : make_uint4(0u, 0u, 0u, 0u);
        int rowB = slot >> 3, c4 = (slot & 7) << 2;
        rbv[i] = *reinterpret_cast<const float4*>(&B[(size_t)rowB * K + c4]);
    }
#pragma unroll
    for (int i = 0; i < 2; ++i) {
        int slot = tid + i * 256;
        int rowA = slot >> 2, c8 = (slot & 3) << 3;
        *reinterpret_cast<uint4*>(&As[rowA * LDT + c8]) = rawA[i];
        int rowB = slot >> 3, c4 = (slot & 7) << 2;
        ushort4 ub = make_ushort4(f2b(rbv[i].x), f2b(rbv[i].y), f2b(rbv[i].z), f2b(rbv[i].w));
        *reinterpret_cast<ushort4*>(&Bs[rowB * LDT + c4]) = ub;
    }
    __syncthreads();

    for (int ks = 0; ks < NK; ++ks) {
        if (ks + 1 < NK) {
            int k0 = (ks + 1) * 32;
#pragma unroll
            for (int i = 0; i < 2; ++i) {
                int slot = tid + i * 256;
                int rowA = slot >> 2, c8 = (slot & 3) << 3;
                int m = m0 + rowA;
                rawA[i] = (m < M) ? *reinterpret_cast<const uint4*>(&A[(size_t)m * K + k0 + c8])
                                  : make_uint4(0u, 0u, 0u, 0u);
                int rowB = slot >> 3, c4 = (slot & 7) << 2;
                rbv[i] = *reinterpret_cast<const float4*>(&B[(size_t)rowB * K + k0 + c4]);
            }
        }
        bf16x8 af[4], bf[2];
#pragma unroll
        for (int f = 0; f < 4; ++f)
            af[f] = *reinterpret_cast<const bf16x8*>(&As[(wm * 64 + f * 16 + l15) * LDT + koff]);
#pragma unroll
        for (int f = 0; f < 2; ++f)
            bf[f] = *reinterpret_cast<const bf16x8*>(&Bs[(wn * 32 + f * 16 + l15) * LDT + koff]);
#pragma unroll
        for (int i = 0; i < 4; ++i)
#pragma unroll
            for (int j = 0; j < 2; ++j)
                acc[i][j] = __builtin_amdgcn_mfma_f32_16x16x32_bf16(af[i], bf[j], acc[i][j], 0, 0, 0);
        __syncthreads();
        if (ks + 1 < NK) {
#pragma unroll
            for (int i = 0; i < 2; ++i) {
                int slot = tid + i * 256;
                int rowA = slot >> 2, c8 = (slot & 3) << 3;
                *reinterpret_cast<uint4*>(&As[rowA * LDT + c8]) = rawA[i];
                int rowB = slot >> 3, c4 = (slot & 7) << 2;
                ushort4 ub = make_ushort4(f2b(rbv[i].x), f2b(rbv[i].y), f2b(rbv[i].z), f2b(rbv[i].w));
                *reinterpret_cast<ushort4*>(&Bs[rowB * LDT + c4]) = ub;
            }
            __syncthreads();
        }
    }

    const int lr = (lane >> 4) * 4;
#pragma unroll
    for (int nf = 0; nf < 2; ++nf) {
        int col = wn * 32 + nf * 16 + l15;
        float bv = bias[col];
#pragma unroll
        for (int mf = 0; mf < 4; ++mf) {
#pragma unroll
            for (int j = 0; j < 4; ++j) {
                int row = m0 + wm * 64 + mf * 16 + lr + j;
                if (row < M)
                    Cb[(size_t)row * OUT_DIM + col] = f2b(acc[mf][nf][j] + bv);
            }
        }
    }
}

// ---------------- cooperative persistent propagation: all 5 iters, 1 kernel ---
// Grid-stride over nodes (half-wave = node); __threadfence + grid.sync between
// iterations; iteration 5 fused with log-softmax.

__global__ __launch_bounds__(256, 8) void prop5_kernel(
        const uint* __restrict__ hb, const float* __restrict__ dinv,
        const int* __restrict__ offs, const uint* __restrict__ edat,
        uint* xsa, uint* xsb, float* __restrict__ out, int N) {
    cg::grid_group grid = cg::this_grid();
    const int l32   = threadIdx.x & 31;
    const int slot  = threadIdx.x >> 5;         // 0..7
    const int start = blockIdx.x * 8 + slot;
    const int stride = gridDim.x * 8;

    const uint* xin = hb;
    uint* xout = xsa;
#pragma unroll 1
    for (int it = 0; it < 5; ++it) {
        const bool last = (it == 4);
        for (int node = start; node < N; node += stride) {
            const int e0 = offs[node], e1 = offs[node + 1];
            float ax0 = 0.f, ax1 = 0.f, ax2 = 0.f, ax3 = 0.f;
            float ay0 = 0.f, ay1 = 0.f, ay2 = 0.f, ay3 = 0.f;
            int e = e0;
            for (; e + 8 <= e1; e += 8) {
                uint p0 = edat[e+0], p1 = edat[e+1], p2 = edat[e+2], p3 = edat[e+3];
                uint p4 = edat[e+4], p5 = edat[e+5], p6 = edat[e+6], p7 = edat[e+7];
                uint g0 = xin[(size_t)(p0 & 0xFFFFu) * 32 + l32];
                uint g1 = xin[(size_t)(p1 & 0xFFFFu) * 32 + l32];
                uint g2 = xin[(size_t)(p2 & 0xFFFFu) * 32 + l32];
                uint g3 = xin[(size_t)(p3 & 0xFFFFu) * 32 + l32];
                uint g4 = xin[(size_t)(p4 & 0xFFFFu) * 32 + l32];
                uint g5 = xin[(size_t)(p5 & 0xFFFFu) * 32 + l32];
                uint g6 = xin[(size_t)(p6 & 0xFFFFu) * 32 + l32];
                uint g7 = xin[(size_t)(p7 & 0xFFFFu) * 32 + l32];
                ax0 = fmaf(b2f_hi(p0), b2f_lo(g0), ax0); ay0 = fmaf(b2f_hi(p0), b2f_hi(g0), ay0);
                ax1 = fmaf(b2f_hi(p1), b2f_lo(g1), ax1); ay1 = fmaf(b2f_hi(p1), b2f_hi(g1), ay1);
                ax2 = fmaf(b2f_hi(p2), b2f_lo(g2), ax2); ay2 = fmaf(b2f_hi(p2), b2f_hi(g2), ay2);
                ax3 = fmaf(b2f_hi(p3), b2f_lo(g3), ax3); ay3 = fmaf(b2f_hi(p3), b2f_hi(g3), ay3);
                ax0 = fmaf(b2f_hi(p4), b2f_lo(g4), ax0); ay0 = fmaf(b2f_hi(p4), b2f_hi(g4), ay0);
                ax1 = fmaf(b2f_hi(p5), b2f_lo(g5), ax1); ay1 = fmaf(b2f_hi(p5), b2f_hi(g5), ay1);
                ax2 = fmaf(b2f_hi(p6), b2f_lo(g6), ax2); ay2 = fmaf(b2f_hi(p6), b2f_hi(g6), ay2);
                ax3 = fmaf(b2f_hi(p7), b2f_lo(g7), ax3); ay3 = fmaf(b2f_hi(p7), b2f_hi(g7), ay3);
            }
            for (; e < e1; ++e) {
                uint p = edat[e];
                uint g = xin[(size_t)(p & 0xFFFFu) * 32 + l32];
                ax0 = fmaf(b2f_hi(p), b2f_lo(g), ax0);
                ay0 = fmaf(b2f_hi(p), b2f_hi(g), ay0);
            }
            float sx = (ax0 + ax1) + (ax2 + ax3);
            float sy = (ay0 + ay1) + (ay2 + ay3);
            float di = dinv[node];
            uint gs = xin[(size_t)node * 32 + l32];
            sx = fmaf(di * di, b2f_lo(gs), sx);
            sy = fmaf(di * di, b2f_hi(gs), sy);
            uint ah = hb[(size_t)node * 32 + l32];
            float r0 = 0.9f * sx + 0.1f * b2f_lo(ah);
            float r1 = 0.9f * sy + 0.1f * b2f_hi(ah);
            if (!last) {
                xout[(size_t)node * 32 + l32] = packbf(r0, r1);
            } else {
                float m = fmaxf(r0, r1);
                for (int o = 16; o > 0; o >>= 1) m = fmaxf(m, __shfl_xor(m, o));
                float sum = expf(r0 - m) + expf(r1 - m);
                for (int o = 16; o > 0; o >>= 1) sum += __shfl_xor(sum, o);
                float ls = logf(sum);
                float2 o2 = make_float2(r0 - m - ls, r1 - m - ls);
                *reinterpret_cast<float2*>(&out[(size_t)node * 64 + l32 * 2]) = o2;
            }
        }
        if (it < 4) {
            __threadfence();
            grid.sync();
            xin = xout;
            xout = (xout == xsa) ? xsb : xsa;
        }
    }
}

// ---------------- fallback separate propagation kernels (validated path) ------

__global__ __launch_bounds__(256) void propb_kernel(const uint* __restrict__ xin,
                                                    const uint* __restrict__ hb,
                                                    const float* __restrict__ dinv,
                                                    const int* __restrict__ offs,
                                                    const uint* __restrict__ edat,
                                                    uint* __restrict__ xout, int N) {
    int node = blockIdx.x * 8 + (threadIdx.x >> 5);
    int l32 = threadIdx.x & 31;
    if (node >= N) return;
    int e0 = offs[node], e1 = offs[node + 1];

    float ax[4] = {0.f, 0.f, 0.f, 0.f};
    float ay[4] = {0.f, 0.f, 0.f, 0.f};
    int e = e0;
    for (; e + 8 <= e1; e += 8) {
        uint p[8], g[8];
#pragma unroll
        for (int i = 0; i < 8; ++i) p[i] = edat[e + i];
#pragma unroll
        for (int i = 0; i < 8; ++i) g[i] = xin[(size_t)(p[i] & 0xFFFFu) * 32 + l32];
#pragma unroll
        for (int i = 0; i < 8; ++i) {
            float wgt = b2f_hi(p[i]);
            ax[i & 3] = fmaf(wgt, b2f_lo(g[i]), ax[i & 3]);
            ay[i & 3] = fmaf(wgt, b2f_hi(g[i]), ay[i & 3]);
        }
    }
    for (; e < e1; ++e) {
        uint p = edat[e];
        uint g = xin[(size_t)(p & 0xFFFFu) * 32 + l32];
        ax[0] = fmaf(b2f_hi(p), b2f_lo(g), ax[0]);
        ay[0] = fmaf(b2f_hi(p), b2f_hi(g), ay[0]);
    }
    float sx = (ax[0] + ax[1]) + (ax[2] + ax[3]);
    float sy = (ay[0] + ay[1]) + (ay[2] + ay[3]);
    float di = dinv[node];
    uint gs = xin[(size_t)node * 32 + l32];
    sx = fmaf(di * di, b2f_lo(gs), sx);
    sy = fmaf(di * di, b2f_hi(gs), sy);
    uint ah = hb[(size_t)node * 32 + l32];
    float r0 = 0.9f * sx + 0.1f * b2f_lo(ah);
    float r1 = 0.9f * sy + 0.1f * b2f_hi(ah);
    xout[(size_t)node * 32 + l32] = packbf(r0, r1);
}

__global__ __launch_bounds__(256) void propb_lsm_kernel(const uint* __restrict__ xin,
                                                        const uint* __restrict__ hb,
                                                        const float* __restrict__ dinv,
                                                        const int* __restrict__ offs,
                                                        const uint* __restrict__ edat,
                                                        float* __restrict__ out, int N) {
    int node = blockIdx.x * 8 + (threadIdx.x >> 5);
    int l32 = threadIdx.x & 31;
    if (node >= N) return;
    int e0 = offs[node], e1 = offs[node + 1];

    float ax[4] = {0.f, 0.f, 0.f, 0.f};
    float ay[4] = {0.f, 0.f, 0.f, 0.f};
    int e = e0;
    for (; e + 8 <= e1; e += 8) {
        uint p[8], g[8];
#pragma unroll
        for (int i = 0; i < 8; ++i) p[i] = edat[e + i];
#pragma unroll
        for (int i = 0; i < 8; ++i) g[i] = xin[(size_t)(p[i] & 0xFFFFu) * 32 + l32];
#pragma unroll
        for (int i = 0; i < 8; ++i) {
            float wgt = b2f_hi(p[i]);
            ax[i & 3] = fmaf(wgt, b2f_lo(g[i]), ax[i & 3]);
            ay[i & 3] = fmaf(wgt, b2f_hi(g[i]), ay[i & 3]);
        }
    }
    for (; e < e1; ++e) {
        uint p = edat[e];
        uint g = xin[(size_t)(p & 0xFFFFu) * 32 + l32];
        ax[0] = fmaf(b2f_hi(p), b2f_lo(g), ax[0]);
        ay[0] = fmaf(b2f_hi(p), b2f_hi(g), ay[0]);
    }
    float sx = (ax[0] + ax[1]) + (ax[2] + ax[3]);
    float sy = (ay[0] + ay[1]) + (ay[2] + ay[3]);
    float di = dinv[node];
    uint gs = xin[(size_t)node * 32 + l32];
    sx = fmaf(di * di, b2f_lo(gs), sx);
    sy = fmaf(di * di, b2f_hi(gs), sy);
    uint ah = hb[(size_t)node * 32 + l32];
    float r0 = 0.9f * sx + 0.1f * b2f_lo(ah);
    float r1 = 0.9f * sy + 0.1f * b2f_hi(ah);

    float m = fmaxf(r0, r1);
    for (int o = 16; o > 0; o >>= 1) m = fmaxf(m, __shfl_xor(m, o));
    float sum = expf(r0 - m) + expf(r1 - m);
    for (int o = 16; o > 0; o >>= 1) sum += __shfl_xor(sum, o);
    float ls = logf(sum);
    float2 o2 = make_float2(r0 - m - ls, r1 - m - ls);
    *reinterpret_cast<float2*>(&out[(size_t)node * 64 + l32 * 2]) = o2;
}

// ---------------- launch ----------------

static inline size_t align256(size_t x) { return (x + 255) & ~(size_t)255; }

extern "C" void kernel_launch(void* const* d_in, const int* in_sizes, int n_in,
                              void* d_out, int out_size, void* d_ws, size_t ws_size,
                              hipStream_t stream) {
    const float* x  = (const float*)d_in[0];
    const float* W1 = (const float*)d_in[1];
    const float* b1 = (const float*)d_in[2];
    const float* W2 = (const float*)d_in[3];
    const float* b2 = (const float*)d_in[4];
    const int*   ei = (const int*)d_in[5];

    const int N = in_sizes[0] / IN_DIM;
    const int E = in_sizes[5] / 2;
    const int nb = (N + 255) / 256;

    char* base = (char*)d_ws;
    size_t off = 0;
    uint*  hb  = (uint*)(base + off);    off += align256((size_t)N * 32 * 4);
    uint*  xsa = (uint*)(base + off);    off += align256((size_t)N * 32 * 4);
    uint*  xsb = (uint*)(base + off);    off += align256((size_t)N * 32 * 4);
    ushort* w1b = (ushort*)(base + off); off += align256((size_t)HID_DIM * IN_DIM * 2);
    ushort* h1  = (ushort*)(base + off); off += align256((size_t)N * HID_DIM * 2);
    float* dinv = (float*)(base + off);  off += align256((size_t)N * 4);
    int*   deg  = (int*)(base + off);    off += align256((size_t)N * 4);
    int*   offs = (int*)(base + off);    off += align256((size_t)(N + 1) * 4);
    int*   cur  = (int*)(base + off);    off += align256((size_t)N * 4);
    int*   bsum = (int*)(base + off);    off += align256((size_t)nb * 4);
    uint*  edat = (uint*)(base + off);   off += align256((size_t)E * 4);

    // ---- CSR build ----
    hipMemsetAsync(deg, 0, (size_t)N * 4, stream);
    hipMemsetAsync(cur, 0, (size_t)N * 4, stream);
    hist_kernel<<<(E + 255) / 256, 256, 0, stream>>>(ei, deg, E);
    scanA_kernel<<<nb, 256, 0, stream>>>(deg, offs, bsum, N);
    scanB_kernel<<<1, 256, 0, stream>>>(bsum, nb);
    scanC_kernel<<<nb, 256, 0, stream>>>(deg, bsum, offs, dinv, N, E);
    fill_kernel<<<(E + 255) / 256, 256, 0, stream>>>(ei, offs, cur, dinv, edat, E);

    // ---- W1 -> bf16 ----
    f2b_kernel<<<64, 256, 0, stream>>>(W1, w1b, HID_DIM * IN_DIM / 8);

    // ---- MLP (bf16 MFMA) ----
    {
        dim3 g(HID_DIM / 128, (N + 127) / 128);
        gemm1_f32a<<<g, 256, 0, stream>>>(x, w1b, b1, h1, N);
    }
    {
        dim3 g((N + 127) / 128);
        gemm2_bf16<<<g, 256, 0, stream>>>(h1, W2, b2, (ushort*)hb, N);
    }

    // ---- K propagation steps: one cooperative persistent kernel ----
    {
        float* outp = (float*)d_out;
        int Nv = N;
        void* kargs[] = { (void*)&hb, (void*)&dinv, (void*)&offs, (void*)&edat,
                          (void*)&xsa, (void*)&xsb, (void*)&outp, (void*)&Nv };
        hipError_t ce = hipLaunchCooperativeKernel((const void*)prop5_kernel,
                                                   dim3(2048), dim3(256),
                                                   kargs, 0, stream);
        if (ce != hipSuccess) {
            // fallback: validated 5-kernel path (identical math)
            int blocks = (N + 7) / 8;
            propb_kernel<<<blocks, 256, 0, stream>>>(hb,  hb, dinv, offs, edat, xsa, N);
            propb_kernel<<<blocks, 256, 0, stream>>>(xsa, hb, dinv, offs, edat, xsb, N);
            propb_kernel<<<blocks, 256, 0, stream>>>(xsb, hb, dinv, offs, edat, xsa, N);
            propb_kernel<<<blocks, 256, 0, stream>>>(xsa, hb, dinv, offs, edat, xsb, N);
            propb_lsm_kernel<<<blocks, 256, 0, stream>>>(xsb, hb, dinv, offs, edat,
                                                         (float*)d_out, N);
        }
    }
}

// Round 13
// 270.436 us; speedup vs baseline: 7.7467x; 7.7467x over previous
//
#include <hip/hip_runtime.h>
#include <hip/hip_bf16.h>

#define IN_DIM  512
#define HID_DIM 256
#define OUT_DIM 64

typedef __attribute__((ext_vector_type(8))) short bf16x8;
typedef __attribute__((ext_vector_type(4))) float f32x4;

static __device__ __forceinline__ ushort f2b(float f) {
    __hip_bfloat16 b = __float2bfloat16(f);
    return *reinterpret_cast<ushort*>(&b);
}
static __device__ __forceinline__ float b2f_lo(uint u) {
    union { uint u; float f; } t; t.u = u << 16; return t.f;
}
static __device__ __forceinline__ float b2f_hi(uint u) {
    union { uint u; float f; } t; t.u = u & 0xFFFF0000u; return t.f;
}
static __device__ __forceinline__ uint packbf(float x, float y) {
    return (uint)f2b(x) | ((uint)f2b(y) << 16);
}

#define GLOAD16(g, l) __builtin_amdgcn_global_load_lds(                      \
    (const __attribute__((address_space(1))) void*)(g),                      \
    (__attribute__((address_space(3))) void*)(l), 16, 0, 0)

// ---------------- fp32 -> bf16 bulk convert (W1 only) ----------------

__global__ __launch_bounds__(256) void f2b_kernel(const float* __restrict__ in,
                                                  ushort* __restrict__ out, int n8) {
    for (int i = blockIdx.x * 256 + threadIdx.x; i < n8; i += gridDim.x * 256) {
        float4 a = *reinterpret_cast<const float4*>(&in[(size_t)i * 8]);
        float4 b = *reinterpret_cast<const float4*>(&in[(size_t)i * 8 + 4]);
        ushort4 lo = make_ushort4(f2b(a.x), f2b(a.y), f2b(a.z), f2b(a.w));
        ushort4 hi = make_ushort4(f2b(b.x), f2b(b.y), f2b(b.z), f2b(b.w));
        *reinterpret_cast<ushort4*>(&out[(size_t)i * 8])     = lo;
        *reinterpret_cast<ushort4*>(&out[(size_t)i * 8 + 4]) = hi;
    }
}

// ---------------- CSR build ----------------

__global__ void hist_kernel(const int* __restrict__ ei, int* __restrict__ deg, int E) {
    int e = blockIdx.x * 256 + threadIdx.x;
    if (e < E) atomicAdd(&deg[ei[E + e]], 1);
}

__global__ __launch_bounds__(256) void scanA_kernel(const int* __restrict__ deg,
                                                    int* __restrict__ offs,
                                                    int* __restrict__ bsum, int N) {
    __shared__ int sh[256];
    int tid = threadIdx.x;
    int i = blockIdx.x * 256 + tid;
    int v = (i < N) ? deg[i] : 0;
    sh[tid] = v;
    __syncthreads();
#pragma unroll
    for (int off = 1; off < 256; off <<= 1) {
        int t = (tid >= off) ? sh[tid - off] : 0;
        __syncthreads();
        sh[tid] += t;
        __syncthreads();
    }
    if (i < N) offs[i] = sh[tid] - v;
    if (tid == 255) bsum[blockIdx.x] = sh[255];
}

__global__ __launch_bounds__(256) void scanB_kernel(int* __restrict__ bsum, int nb) {
    __shared__ int sh[256];
    int tid = threadIdx.x;
    int v = (tid < nb) ? bsum[tid] : 0;
    sh[tid] = v;
    __syncthreads();
#pragma unroll
    for (int off = 1; off < 256; off <<= 1) {
        int t = (tid >= off) ? sh[tid - off] : 0;
        __syncthreads();
        sh[tid] += t;
        __syncthreads();
    }
    if (tid < nb) bsum[tid] = sh[tid] - v;
}

__global__ __launch_bounds__(256) void scanC_kernel(const int* __restrict__ deg,
                                                    const int* __restrict__ bsum,
                                                    int* __restrict__ offs,
                                                    float* __restrict__ dinv,
                                                    int N, int E) {
    int i = blockIdx.x * 256 + threadIdx.x;
    if (i < N) {
        offs[i] += bsum[i >> 8];
        dinv[i] = rsqrtf((float)(deg[i] + 1));
    }
    if (i == 0) offs[N] = E;
}

// edat[pos] = src(u16) | f2b(w)<<16  -- 4B per edge
__global__ void fill_kernel(const int* __restrict__ ei, const int* __restrict__ offs,
                            int* __restrict__ cursor, const float* __restrict__ dinv,
                            uint* __restrict__ edat, int E) {
    int e = blockIdx.x * 256 + threadIdx.x;
    if (e < E) {
        int s = ei[e];
        int d = ei[E + e];
        int pos = offs[d] + atomicAdd(&cursor[d], 1);
        edat[pos] = (uint)s | ((uint)f2b(dinv[d] * dinv[s]) << 16);
    }
}

// ---------------- GEMM1 (r6-best, measured 64us): BK=64 single-buffer ----------

__global__ __launch_bounds__(256) void gemm1_f32a(const float* __restrict__ A,
                                                  const ushort* __restrict__ B,
                                                  const float* __restrict__ bias,
                                                  ushort* __restrict__ C, int M) {
    constexpr int K = IN_DIM;       // 512
    constexpr int NK = K / 64;      // 8 K-steps
    __shared__ float  Asf[128 * 64];   // 32KB fp32 A-tile
    __shared__ ushort Bs[128 * 64];    // 16KB bf16 B-tile

    const int tid  = threadIdx.x;
    const int lane = tid & 63;
    const int wid  = tid >> 6;
    const int wm = wid >> 1, wn = wid & 1;
    const int m0 = blockIdx.y * 128;
    const int n0 = blockIdx.x * 128;
    const int l15 = lane & 15;
    const int lq  = lane >> 4;

    const int a_r   = lane >> 4;
    const int a_s16 = lane & 15;
    const int a_pair = a_s16 >> 1, a_sub = a_s16 & 1;
    const int srow  = lane >> 3;
    const int sslot = (lane & 7) ^ srow;

    f32x4 acc[4][4];
#pragma unroll
    for (int i = 0; i < 4; ++i)
#pragma unroll
        for (int j = 0; j < 4; ++j) acc[i][j] = (f32x4)0.0f;

    for (int ks = 0; ks < NK; ++ks) {
        const int k0 = ks * 64;
#pragma unroll
        for (int q = 0; q < 4; ++q) {
            const int rbase = (wid * 4 + q) * 8;
            const int row = rbase + srow;
            const ushort* gb = B + (size_t)(n0 + row) * K + k0 + sslot * 8;
            GLOAD16(gb, &Bs[rbase * 64]);
        }
#pragma unroll
        for (int q = 0; q < 8; ++q) {
            const int rbase = (wid * 8 + q) * 4;
            const int row = rbase + a_r;
            int am = m0 + row; if (am >= M) am = M - 1;
            const int col = k0 + ((a_pair ^ (row & 7)) << 3) + (a_sub << 2);
            const float* ga = A + (size_t)am * K + col;
            GLOAD16(ga, &Asf[rbase * 64]);
        }
        __syncthreads();
#pragma unroll
        for (int kk = 0; kk < 2; ++kk) {
            const int p = kk * 4 + lq;
            bf16x8 af[4], bf[4];
#pragma unroll
            for (int f = 0; f < 4; ++f) {
                const int ar = wm * 64 + f * 16 + l15;
                const int fi = ar * 64 + ((p ^ (ar & 7)) << 3);
                f32x4 v0 = *reinterpret_cast<const f32x4*>(&Asf[fi]);
                f32x4 v1 = *reinterpret_cast<const f32x4*>(&Asf[fi + 4]);
                bf16x8 a;
                a[0] = (short)f2b(v0[0]); a[1] = (short)f2b(v0[1]);
                a[2] = (short)f2b(v0[2]); a[3] = (short)f2b(v0[3]);
                a[4] = (short)f2b(v1[0]); a[5] = (short)f2b(v1[1]);
                a[6] = (short)f2b(v1[2]); a[7] = (short)f2b(v1[3]);
                af[f] = a;
                const int br = wn * 64 + f * 16 + l15;
                bf[f] = *reinterpret_cast<const bf16x8*>(&Bs[br * 64 + ((p ^ (br & 7)) << 3)]);
            }
#pragma unroll
            for (int i = 0; i < 4; ++i)
#pragma unroll
                for (int j = 0; j < 4; ++j)
                    acc[i][j] = __builtin_amdgcn_mfma_f32_16x16x32_bf16(af[i], bf[j], acc[i][j], 0, 0, 0);
        }
        __syncthreads();
    }

    const int lr = lq * 4;
#pragma unroll
    for (int nf = 0; nf < 4; ++nf) {
        int col = n0 + wn * 64 + nf * 16 + l15;
        float bv = bias[col];
#pragma unroll
        for (int mf = 0; mf < 4; ++mf) {
#pragma unroll
            for (int j = 0; j < 4; ++j) {
                int row = m0 + wm * 64 + mf * 16 + lr + j;
                if (row < M) {
                    float v = fmaxf(acc[mf][nf][j] + bv, 0.f);
                    C[(size_t)row * HID_DIM + col] = f2b(v);
                }
            }
        }
    }
}

// ---------------- GEMM2: hb[M,64] = bf16(h1_bf16[M,256] @ W2[64,256]^T + b2) ----

#define LDT 40

__global__ __launch_bounds__(256) void gemm2_bf16(const ushort* __restrict__ A,
                                                  const float* __restrict__ B,
                                                  const float* __restrict__ bias,
                                                  ushort* __restrict__ Cb,
                                                  int M) {
    constexpr int K = HID_DIM;
    constexpr int NK = K / 32;
    __shared__ ushort As[128 * LDT];
    __shared__ ushort Bs[64 * LDT];

    const int tid = threadIdx.x;
    const int lane = tid & 63;
    const int wid = tid >> 6;
    const int wm = wid >> 1, wn = wid & 1;
    const int m0 = blockIdx.x * 128;
    const int l15 = lane & 15;
    const int koff = (lane >> 4) * 8;

    f32x4 acc[4][2];
#pragma unroll
    for (int i = 0; i < 4; ++i)
#pragma unroll
        for (int j = 0; j < 2; ++j) acc[i][j] = (f32x4)0.0f;

    uint4 rawA[2];
    float4 rbv[2];
#pragma unroll
    for (int i = 0; i < 2; ++i) {
        int slot = tid + i * 256;
        int rowA = slot >> 2, c8 = (slot & 3) << 3;
        int m = m0 + rowA;
        rawA[i] = (m < M) ? *reinterpret_cast<const uint4*>(&A[(size_t)m * K + c8])
                          : make_uint4(0u, 0u, 0u, 0u);
        int rowB = slot >> 3, c4 = (slot & 7) << 2;
        rbv[i] = *reinterpret_cast<const float4*>(&B[(size_t)rowB * K + c4]);
    }
#pragma unroll
    for (int i = 0; i < 2; ++i) {
        int slot = tid + i * 256;
        int rowA = slot >> 2, c8 = (slot & 3) << 3;
        *reinterpret_cast<uint4*>(&As[rowA * LDT + c8]) = rawA[i];
        int rowB = slot >> 3, c4 = (slot & 7) << 2;
        ushort4 ub = make_ushort4(f2b(rbv[i].x), f2b(rbv[i].y), f2b(rbv[i].z), f2b(rbv[i].w));
        *reinterpret_cast<ushort4*>(&Bs[rowB * LDT + c4]) = ub;
    }
    __syncthreads();

    for (int ks = 0; ks < NK; ++ks) {
        if (ks + 1 < NK) {
            int k0 = (ks + 1) * 32;
#pragma unroll
            for (int i = 0; i < 2; ++i) {
                int slot = tid + i * 256;
                int rowA = slot >> 2, c8 = (slot & 3) << 3;
                int m = m0 + rowA;
                rawA[i] = (m < M) ? *reinterpret_cast<const uint4*>(&A[(size_t)m * K + k0 + c8])
                                  : make_uint4(0u, 0u, 0u, 0u);
                int rowB = slot >> 3, c4 = (slot & 7) << 2;
                rbv[i] = *reinterpret_cast<const float4*>(&B[(size_t)rowB * K + k0 + c4]);
            }
        }
        bf16x8 af[4], bf[2];
#pragma unroll
        for (int f = 0; f < 4; ++f)
            af[f] = *reinterpret_cast<const bf16x8*>(&As[(wm * 64 + f * 16 + l15) * LDT + koff]);
#pragma unroll
        for (int f = 0; f < 2; ++f)
            bf[f] = *reinterpret_cast<const bf16x8*>(&Bs[(wn * 32 + f * 16 + l15) * LDT + koff]);
#pragma unroll
        for (int i = 0; i < 4; ++i)
#pragma unroll
            for (int j = 0; j < 2; ++j)
                acc[i][j] = __builtin_amdgcn_mfma_f32_16x16x32_bf16(af[i], bf[j], acc[i][j], 0, 0, 0);
        __syncthreads();
        if (ks + 1 < NK) {
#pragma unroll
            for (int i = 0; i < 2; ++i) {
                int slot = tid + i * 256;
                int rowA = slot >> 2, c8 = (slot & 3) << 3;
                *reinterpret_cast<uint4*>(&As[rowA * LDT + c8]) = rawA[i];
                int rowB = slot >> 3, c4 = (slot & 7) << 2;
                ushort4 ub = make_ushort4(f2b(rbv[i].x), f2b(rbv[i].y), f2b(rbv[i].z), f2b(rbv[i].w));
                *reinterpret_cast<ushort4*>(&Bs[rowB * LDT + c4]) = ub;
            }
            __syncthreads();
        }
    }

    const int lr = (lane >> 4) * 4;
#pragma unroll
    for (int nf = 0; nf < 2; ++nf) {
        int col = wn * 32 + nf * 16 + l15;
        float bv = bias[col];
#pragma unroll
        for (int mf = 0; mf < 4; ++mf) {
#pragma unroll
            for (int j = 0; j < 4; ++j) {
                int row = m0 + wm * 64 + mf * 16 + lr + j;
                if (row < M)
                    Cb[(size_t)row * OUT_DIM + col] = f2b(acc[mf][nf][j] + bv);
            }
        }
    }
}

// ---------------- bf16 propagation (validated): wave = 2 nodes, 16-wide bursts -

__global__ __launch_bounds__(256) void propb_kernel(const uint* __restrict__ xin,
                                                    const uint* __restrict__ hb,
                                                    const float* __restrict__ dinv,
                                                    const int* __restrict__ offs,
                                                    const uint* __restrict__ edat,
                                                    uint* __restrict__ xout, int N) {
    int node = blockIdx.x * 8 + (threadIdx.x >> 5);
    int l32 = threadIdx.x & 31;
    if (node >= N) return;
    int e0 = offs[node], e1 = offs[node + 1];

    float ax[4] = {0.f, 0.f, 0.f, 0.f};
    float ay[4] = {0.f, 0.f, 0.f, 0.f};
    int e = e0;
    for (; e + 16 <= e1; e += 16) {
        uint p[16], g[16];
#pragma unroll
        for (int i = 0; i < 16; ++i) p[i] = edat[e + i];
#pragma unroll
        for (int i = 0; i < 16; ++i) g[i] = xin[(size_t)(p[i] & 0xFFFFu) * 32 + l32];
#pragma unroll
        for (int i = 0; i < 16; ++i) {
            float wgt = b2f_hi(p[i]);
            ax[i & 3] = fmaf(wgt, b2f_lo(g[i]), ax[i & 3]);
            ay[i & 3] = fmaf(wgt, b2f_hi(g[i]), ay[i & 3]);
        }
    }
    for (; e + 4 <= e1; e += 4) {
        uint p[4], g[4];
#pragma unroll
        for (int i = 0; i < 4; ++i) p[i] = edat[e + i];
#pragma unroll
        for (int i = 0; i < 4; ++i) g[i] = xin[(size_t)(p[i] & 0xFFFFu) * 32 + l32];
#pragma unroll
        for (int i = 0; i < 4; ++i) {
            float wgt = b2f_hi(p[i]);
            ax[i] = fmaf(wgt, b2f_lo(g[i]), ax[i]);
            ay[i] = fmaf(wgt, b2f_hi(g[i]), ay[i]);
        }
    }
    for (; e < e1; ++e) {
        uint p = edat[e];
        uint g = xin[(size_t)(p & 0xFFFFu) * 32 + l32];
        ax[0] = fmaf(b2f_hi(p), b2f_lo(g), ax[0]);
        ay[0] = fmaf(b2f_hi(p), b2f_hi(g), ay[0]);
    }
    float sx = (ax[0] + ax[1]) + (ax[2] + ax[3]);
    float sy = (ay[0] + ay[1]) + (ay[2] + ay[3]);
    float di = dinv[node];
    uint gs = xin[(size_t)node * 32 + l32];
    sx = fmaf(di * di, b2f_lo(gs), sx);
    sy = fmaf(di * di, b2f_hi(gs), sy);
    uint ah = hb[(size_t)node * 32 + l32];
    float r0 = 0.9f * sx + 0.1f * b2f_lo(ah);
    float r1 = 0.9f * sy + 0.1f * b2f_hi(ah);
    xout[(size_t)node * 32 + l32] = packbf(r0, r1);
}

// final propagation fused with log-softmax (fp32 output)

__global__ __launch_bounds__(256) void propb_lsm_kernel(const uint* __restrict__ xin,
                                                        const uint* __restrict__ hb,
                                                        const float* __restrict__ dinv,
                                                        const int* __restrict__ offs,
                                                        const uint* __restrict__ edat,
                                                        float* __restrict__ out, int N) {
    int node = blockIdx.x * 8 + (threadIdx.x >> 5);
    int l32 = threadIdx.x & 31;
    if (node >= N) return;
    int e0 = offs[node], e1 = offs[node + 1];

    float ax[4] = {0.f, 0.f, 0.f, 0.f};
    float ay[4] = {0.f, 0.f, 0.f, 0.f};
    int e = e0;
    for (; e + 16 <= e1; e += 16) {
        uint p[16], g[16];
#pragma unroll
        for (int i = 0; i < 16; ++i) p[i] = edat[e + i];
#pragma unroll
        for (int i = 0; i < 16; ++i) g[i] = xin[(size_t)(p[i] & 0xFFFFu) * 32 + l32];
#pragma unroll
        for (int i = 0; i < 16; ++i) {
            float wgt = b2f_hi(p[i]);
            ax[i & 3] = fmaf(wgt, b2f_lo(g[i]), ax[i & 3]);
            ay[i & 3] = fmaf(wgt, b2f_hi(g[i]), ay[i & 3]);
        }
    }
    for (; e + 4 <= e1; e += 4) {
        uint p[4], g[4];
#pragma unroll
        for (int i = 0; i < 4; ++i) p[i] = edat[e + i];
#pragma unroll
        for (int i = 0; i < 4; ++i) g[i] = xin[(size_t)(p[i] & 0xFFFFu) * 32 + l32];
#pragma unroll
        for (int i = 0; i < 4; ++i) {
            float wgt = b2f_hi(p[i]);
            ax[i] = fmaf(wgt, b2f_lo(g[i]), ax[i]);
            ay[i] = fmaf(wgt, b2f_hi(g[i]), ay[i]);
        }
    }
    for (; e < e1; ++e) {
        uint p = edat[e];
        uint g = xin[(size_t)(p & 0xFFFFu) * 32 + l32];
        ax[0] = fmaf(b2f_hi(p), b2f_lo(g), ax[0]);
        ay[0] = fmaf(b2f_hi(p), b2f_hi(g), ay[0]);
    }
    float sx = (ax[0] + ax[1]) + (ax[2] + ax[3]);
    float sy = (ay[0] + ay[1]) + (ay[2] + ay[3]);
    float di = dinv[node];
    uint gs = xin[(size_t)node * 32 + l32];
    sx = fmaf(di * di, b2f_lo(gs), sx);
    sy = fmaf(di * di, b2f_hi(gs), sy);
    uint ah = hb[(size_t)node * 32 + l32];
    float r0 = 0.9f * sx + 0.1f * b2f_lo(ah);
    float r1 = 0.9f * sy + 0.1f * b2f_hi(ah);

    float m = fmaxf(r0, r1);
    for (int o = 16; o > 0; o >>= 1) m = fmaxf(m, __shfl_xor(m, o));
    float sum = expf(r0 - m) + expf(r1 - m);
    for (int o = 16; o > 0; o >>= 1) sum += __shfl_xor(sum, o);
    float ls = logf(sum);
    float2 o2 = make_float2(r0 - m - ls, r1 - m - ls);
    *reinterpret_cast<float2*>(&out[(size_t)node * 64 + l32 * 2]) = o2;
}

// ---------------- launch ----------------

static inline size_t align256(size_t x) { return (x + 255) & ~(size_t)255; }

extern "C" void kernel_launch(void* const* d_in, const int* in_sizes, int n_in,
                              void* d_out, int out_size, void* d_ws, size_t ws_size,
                              hipStream_t stream) {
    const float* x  = (const float*)d_in[0];
    const float* W1 = (const float*)d_in[1];
    const float* b1 = (const float*)d_in[2];
    const float* W2 = (const float*)d_in[3];
    const float* b2 = (const float*)d_in[4];
    const int*   ei = (const int*)d_in[5];

    const int N = in_sizes[0] / IN_DIM;
    const int E = in_sizes[5] / 2;
    const int nb = (N + 255) / 256;

    char* base = (char*)d_ws;
    size_t off = 0;
    uint*  hb  = (uint*)(base + off);    off += align256((size_t)N * 32 * 4);
    uint*  xsa = (uint*)(base + off);    off += align256((size_t)N * 32 * 4);
    uint*  xsb = (uint*)(base + off);    off += align256((size_t)N * 32 * 4);
    ushort* w1b = (ushort*)(base + off); off += align256((size_t)HID_DIM * IN_DIM * 2);
    ushort* h1  = (ushort*)(base + off); off += align256((size_t)N * HID_DIM * 2);
    float* dinv = (float*)(base + off);  off += align256((size_t)N * 4);
    int*   deg  = (int*)(base + off);    off += align256((size_t)N * 4);
    int*   offs = (int*)(base + off);    off += align256((size_t)(N + 1) * 4);
    int*   cur  = (int*)(base + off);    off += align256((size_t)N * 4);
    int*   bsum = (int*)(base + off);    off += align256((size_t)nb * 4);
    uint*  edat = (uint*)(base + off);   off += align256((size_t)E * 4);

    // ---- CSR build ----
    hipMemsetAsync(deg, 0, (size_t)N * 4, stream);
    hipMemsetAsync(cur, 0, (size_t)N * 4, stream);
    hist_kernel<<<(E + 255) / 256, 256, 0, stream>>>(ei, deg, E);
    scanA_kernel<<<nb, 256, 0, stream>>>(deg, offs, bsum, N);
    scanB_kernel<<<1, 256, 0, stream>>>(bsum, nb);
    scanC_kernel<<<nb, 256, 0, stream>>>(deg, bsum, offs, dinv, N, E);
    fill_kernel<<<(E + 255) / 256, 256, 0, stream>>>(ei, offs, cur, dinv, edat, E);

    // ---- W1 -> bf16 ----
    f2b_kernel<<<64, 256, 0, stream>>>(W1, w1b, HID_DIM * IN_DIM / 8);

    // ---- MLP (bf16 MFMA) ----
    {
        dim3 g(HID_DIM / 128, (N + 127) / 128);
        gemm1_f32a<<<g, 256, 0, stream>>>(x, w1b, b1, h1, N);
    }
    {
        dim3 g((N + 127) / 128);
        gemm2_bf16<<<g, 256, 0, stream>>>(h1, W2, b2, (ushort*)hb, N);
    }

    // ---- K propagation steps (bf16 state; last fused w/ log-softmax) ----
    int blocks = (N + 7) / 8;
    propb_kernel<<<blocks, 256, 0, stream>>>(hb,  hb, dinv, offs, edat, xsa, N);  // 1
    propb_kernel<<<blocks, 256, 0, stream>>>(xsa, hb, dinv, offs, edat, xsb, N);  // 2
    propb_kernel<<<blocks, 256, 0, stream>>>(xsb, hb, dinv, offs, edat, xsa, N);  // 3
    propb_kernel<<<blocks, 256, 0, stream>>>(xsa, hb, dinv, offs, edat, xsb, N);  // 4
    propb_lsm_kernel<<<blocks, 256, 0, stream>>>(xsb, hb, dinv, offs, edat,
                                                 (float*)d_out, N);               // 5 + lsm
}